// Round 2
// baseline (49.672 us; speedup 1.0000x reference)
//
#include <hip/hip_runtime.h>

// Problem constants (match reference)
#define DD 128    // directions
#define OO 256    // out_channels
#define KK 2304   // reduction length (3*3*256)

// out[d,o] = (sum_k w[d,o,k] * x[d,k]) > bias[d,o] ? 1 : 0   (int32 output)
//
// One wave (64 lanes) per output element. Block = 256 threads = 4 waves,
// all 4 waves share the same direction d (so x[d,:] staged once in LDS).
// Weight row is 2304 contiguous floats = 9 iterations of float4/lane.
__global__ __launch_bounds__(256) void binconv_thresh_kernel(
    const float* __restrict__ w,     // [D, O, K]
    const float* __restrict__ bias,  // [D, O]
    const int*   __restrict__ x,     // [D, K]  0/1
    int*         __restrict__ out)   // [D, O]  0/1 int32
{
    __shared__ float xs[KK];

    const int tid  = threadIdx.x;
    const int wave = tid >> 6;       // 0..3
    const int lane = tid & 63;

    // grid = D * (O/4) = 128 * 64 = 8192 blocks
    const int d  = blockIdx.x >> 6;          // 0..127
    const int ob = (blockIdx.x & 63) << 2;   // 0,4,...,252

    // Stage x[d, :] into LDS as float (2304 / 256 = 9 iters, coalesced)
    const int* xrow = x + (size_t)d * KK;
    #pragma unroll
    for (int i = 0; i < KK / 256; ++i) {
        int idx = i * 256 + tid;
        xs[idx] = (float)xrow[idx];
    }
    __syncthreads();

    const int o = ob + wave;
    const float* wrow = w + ((size_t)d * OO + o) * (size_t)KK;

    float acc = 0.0f;
    // K = 2304 = 9 * 64 lanes * 4 floats
    #pragma unroll
    for (int it = 0; it < 9; ++it) {
        const int k = (it * 64 + lane) * 4;
        const float4 wv = *reinterpret_cast<const float4*>(wrow + k);
        acc += wv.x * xs[k + 0];
        acc += wv.y * xs[k + 1];
        acc += wv.z * xs[k + 2];
        acc += wv.w * xs[k + 3];
    }

    // Wave-64 butterfly reduction
    #pragma unroll
    for (int off = 32; off > 0; off >>= 1)
        acc += __shfl_down(acc, off, 64);

    if (lane == 0) {
        const size_t oi = (size_t)d * OO + o;
        out[oi] = (acc > bias[oi]) ? 1 : 0;
    }
}

extern "C" void kernel_launch(void* const* d_in, const int* in_sizes, int n_in,
                              void* d_out, int out_size, void* d_ws, size_t ws_size,
                              hipStream_t stream) {
    const float* w    = (const float*)d_in[0];   // weight_noise [D,O,K] f32
    const float* bias = (const float*)d_in[1];   // bias_noise  [D,O]   f32
    const int*   x    = (const int*)  d_in[2];   // x           [D,K]   int32 0/1
    int*         out  = (int*)d_out;             // [D,O] 0/1 int32

    const int grid = DD * (OO / 4);  // 8192 blocks
    binconv_thresh_kernel<<<grid, 256, 0, stream>>>(w, bias, x, out);
}